// Round 6
// baseline (56.931 us; speedup 1.0000x reference)
//
#include <hip/hip_runtime.h>
#include <stdint.h>

#define CIN   128
#define COUT  256
#define HW    56
#define SP    3136      // 56*56
#define NIMG  32
#define NPIX  (NIMG*SP) // 100352
#define KTOT  (CIN*9)   // 1152

typedef unsigned short u16;
typedef unsigned char  u8;
using i32x4 = __attribute__((ext_vector_type(4))) int;

__device__ __forceinline__ u8 sgn_i8(float v) {
  return v > 0.f ? (u8)1 : (v < 0.f ? (u8)0xFF : (u8)0);
}

__device__ __forceinline__ void gl_lds16(const void* g, void* l) {
  __builtin_amdgcn_global_load_lds(
      (const __attribute__((address_space(1))) void*)g,
      (__attribute__((address_space(3))) void*)l, 16, 0, 0);
}

// ---- prepass: binarize + K-transpose weights to i8: wT[o][q*128+c] ----
__global__ void prep_w(const float* __restrict__ w, u8* __restrict__ wT,
                       u8* __restrict__ zerob) {
  int idx = blockIdx.x * 256 + threadIdx.x;
  if (blockIdx.x == 0 && threadIdx.x < 64) ((uint32_t*)zerob)[threadIdx.x] = 0;
  if (idx >= COUT * KTOT) return;
  int o = idx / KTOT;
  int r = idx - o * KTOT;
  int q = r >> 7;
  int c = r & 127;
  wT[idx] = sgn_i8(w[(size_t)(o * CIN + c) * 9 + q]);
}

// ---- prepass: binarize + NCHW->NHWC transpose of x into i8 ----
__global__ void prep_x(const float* __restrict__ x, u8* __restrict__ xt) {
  __shared__ u8 tile[128][36];
  int b = blockIdx.x;            // 32 n * 98 s-chunks
  int n = b / 98;
  int s0 = (b - n * 98) * 32;
  int t = threadIdx.x;
  int tx = t & 31, ty = t >> 5;  // ty in [0,8)
  const float* xb = x + (size_t)n * CIN * SP;
#pragma unroll
  for (int i = 0; i < 16; ++i) {
    int c = ty + (i << 3);                      // 0..127
    tile[c][tx] = sgn_i8(xb[(size_t)c * SP + s0 + tx]);
  }
  __syncthreads();
  int s = t >> 3, cg = t & 7;                   // s 0..31, cg 0..7
  int c0 = cg << 4;
  uint32_t pk[4];
#pragma unroll
  for (int jj = 0; jj < 4; ++jj) {
    uint32_t a0 = tile[c0 + jj * 4 + 0][s];
    uint32_t a1 = tile[c0 + jj * 4 + 1][s];
    uint32_t a2 = tile[c0 + jj * 4 + 2][s];
    uint32_t a3 = tile[c0 + jj * 4 + 3][s];
    pk[jj] = a0 | (a1 << 8) | (a2 << 16) | (a3 << 24);
  }
  u8* dst = xt + (size_t)(n * SP + s0 + s) * CIN + c0;
  uint4 u; u.x = pk[0]; u.y = pk[1]; u.z = pk[2]; u.w = pk[3];
  *(uint4*)dst = u;
}

// ---- main: implicit-GEMM binarized conv with LDS halo B-reuse ----
// tile: 128 Cout x 224 pixels (4 h-rows, image-aligned: 224*14 = 3136).
// B staged ONCE per block as zero-padded halo [6 vh][58 col][128 cin];
// all 9 taps read it at constant slot offsets. A (wT) staged per tap, dbuf.
// 256 thr = 4 waves (2M x 2N), per-wave 64x112, acc[4][7] -> 22 LDS reads
// feed 56 MFMAs per step (LDS-read pressure -39% vs 8-wave 32x112).
// LDS = 48KB halo + 2x16KB A = 80KB -> 2 blocks/CU (8 waves/CU).
__global__ __launch_bounds__(256, 2) void conv_mfma(
    const u8* __restrict__ wT, const u8* __restrict__ xt,
    const float* __restrict__ bias, const u8* __restrict__ zerob,
    float* __restrict__ out) {
  __shared__ u8 halo[49152];    // 384 slots x 128 B (348 real)
  __shared__ u8 As[2][16384];   // [128 Cout][128 cin] per tap, swizzled chunks

  // XCD-chunked swizzle (896 = 8*112, bijective); mt pairs stay adjacent.
  const int bid0 = blockIdx.x;
  const int bid  = (bid0 & 7) * 112 + (bid0 >> 3);
  const int mt  = bid & 1;        // Cout half
  const int nt2 = bid >> 1;       // 0..447
  const int n    = nt2 / 14;      // image
  const int hblk = nt2 - n * 14;  // 4-row block
  const int h0   = hblk * 4;
  const int sp0  = hblk * 224;

  const int t  = threadIdx.x;
  const int wv = t >> 6;          // 0..3
  const int ln = t & 63;

  // staging lane geometry: slot/row = t>>3, chunk = t&7, swizzled source chunk
  const int tRow = t >> 3;                  // 0..31
  const int chs  = (t & 7) ^ (tRow & 7);    // source chunk (XOR involution)

  // ---- prologue: stage halo (12 calls x 32 slots) ----
#pragma unroll
  for (int c = 0; c < 12; ++c) {
    const int slot = c * 32 + tRow;         // 0..383
    const int vh  = slot / 58;
    const int col = slot - vh * 58;
    const int gh  = h0 - 1 + vh;
    const bool valid = (slot < 348) && ((unsigned)gh < HW) && (col >= 1) && (col <= 56);
    const u8* src = valid
        ? xt + (((size_t)(n * SP + gh * HW + col - 1)) << 7) + (chs << 4)
        : zerob;
    gl_lds16(src, &halo[c * 4096 + wv * 1024]);
  }

  // ---- A staging: 4 calls x 32 rows per tap ----
  const u8* wTbase = wT + (size_t)(mt * 128 + tRow) * KTOT + (chs << 4);
  auto stageA = [&](int b, int q) {
#pragma unroll
    for (int c = 0; c < 4; ++c)
      gl_lds16(wTbase + (size_t)c * 32 * KTOT + q * CIN,
               &As[b][c * 4096 + wv * 1024]);
  };
  stageA(0, 0);

  // ---- fragment geometry (2M x 2N wave grid, per-wave 64x112) ----
  const int wm = wv >> 1, wn = wv & 1;
  const int lr = ln & 15, kg = ln >> 4;
  const int kgs0 = kg << 4;
  int rdA[4];
#pragma unroll
  for (int i = 0; i < 4; ++i)
    rdA[i] = (((wm << 6) + (i << 4) + lr) << 7) + ((kg ^ (lr & 7)) << 4);

  int slotj[7];
#pragma unroll
  for (int j = 0; j < 7; ++j) {
    const int px = wn * 112 + j * 16 + lr;  // 0..223
    const int ph = px / 56;
    slotj[j] = (1 + ph) * 58 + (px - ph * 56) + 1;
  }

  i32x4 acc[4][7];
#pragma unroll
  for (int i = 0; i < 4; ++i)
#pragma unroll
    for (int j = 0; j < 7; ++j) acc[i][j] = (i32x4){0, 0, 0, 0};

  constexpr int DC[9] = {-59, -58, -57, -1, 0, 1, 57, 58, 59};

#pragma unroll
  for (int q = 0; q < 9; ++q) {
    __syncthreads();                 // halo + As[q&1] ready
    if (q < 8) stageA((q + 1) & 1, q + 1);
    const int buf = q & 1;
    int ba[7];
#pragma unroll
    for (int j = 0; j < 7; ++j) {
      const int s_t = slotj[j] + DC[q];
      ba[j] = (s_t << 7) + (kgs0 ^ ((s_t & 7) << 4));
    }
#pragma unroll
    for (int kc = 0; kc < 2; ++kc) {
      i32x4 af[4];
#pragma unroll
      for (int i = 0; i < 4; ++i)
        af[i] = *(const i32x4*)&As[buf][rdA[i] ^ (kc << 6)];
#pragma unroll
      for (int j = 0; j < 7; ++j) {
        const i32x4 bf = *(const i32x4*)&halo[ba[j] ^ (kc << 6)];
#pragma unroll
        for (int i = 0; i < 4; ++i)
          acc[i][j] = __builtin_amdgcn_mfma_i32_16x16x64_i8(af[i], bf, acc[i][j], 0, 0, 0);
      }
    }
  }

  // ---- epilogue: C[m][px] -> out[n][m][sp0+px], + sign(bias[m]) ----
  const int mrow = mt * 128 + wm * 64 + kg * 4;
  float* obase = out + (size_t)n * COUT * SP + sp0 + wn * 112 + lr;
#pragma unroll
  for (int i = 0; i < 4; ++i) {
#pragma unroll
    for (int r = 0; r < 4; ++r) {
      const int m = mrow + i * 16 + r;
      const float bv = bias[m];
      const float sb = bv > 0.f ? 1.f : (bv < 0.f ? -1.f : 0.f);
      float* op = obase + (size_t)m * SP;
#pragma unroll
      for (int j = 0; j < 7; ++j)
        op[j * 16] = (float)acc[i][j][r] + sb;
    }
  }
}

// ---- fallback if workspace is too small: direct conv (slow but correct) ----
__global__ void conv_naive(const float* __restrict__ x, const float* __restrict__ w,
                           const float* __restrict__ bias, float* __restrict__ out) {
  int idx = blockIdx.x * 256 + threadIdx.x;
  const int total = NIMG * COUT * SP;
  if (idx >= total) return;
  int sp = idx % SP;
  int o  = (idx / SP) % COUT;
  int nn = idx / (SP * COUT);
  int h = sp / HW, wx = sp - (sp / HW) * HW;
  float acc = 0.f;
  for (int c = 0; c < CIN; ++c) {
    const float* xp = x + (size_t)(nn * CIN + c) * SP;
    const float* wp = w + (size_t)(o * CIN + c) * 9;
    for (int kh = 0; kh < 3; ++kh) {
      int hhh = h + kh - 1;
      if ((unsigned)hhh >= HW) continue;
      for (int kw = 0; kw < 3; ++kw) {
        int www = wx + kw - 1;
        if ((unsigned)www >= HW) continue;
        float xv = xp[hhh * HW + www];
        float wv = wp[kh * 3 + kw];
        float xs = xv > 0.f ? 1.f : (xv < 0.f ? -1.f : 0.f);
        float wsn = wv > 0.f ? 1.f : (wv < 0.f ? -1.f : 0.f);
        acc += xs * wsn;
      }
    }
  }
  float bv = bias[o];
  out[idx] = acc + (bv > 0.f ? 1.f : (bv < 0.f ? -1.f : 0.f));
}

extern "C" void kernel_launch(void* const* d_in, const int* in_sizes, int n_in,
                              void* d_out, int out_size, void* d_ws, size_t ws_size,
                              hipStream_t stream) {
  const float* x    = (const float*)d_in[0];
  const float* w    = (const float*)d_in[1];
  const float* bias = (const float*)d_in[2];
  float* out = (float*)d_out;

  const size_t need = (size_t)1048576 + (size_t)NPIX * CIN;  // ~13.9 MB
  if (ws_size >= need) {
    u8* zerob = (u8*)d_ws;                        // 256 B zeros
    u8* wT8   = (u8*)((char*)d_ws + 512);         // 256x1152 i8
    u8* xt8   = (u8*)((char*)d_ws + 1048576);     // NHWC i8
    prep_w<<<(COUT * KTOT + 255) / 256, 256, 0, stream>>>(w, wT8, zerob);
    prep_x<<<NIMG * 98, 256, 0, stream>>>(x, xt8);
    conv_mfma<<<896, 256, 0, stream>>>(wT8, xt8, bias, zerob, out);
  } else {
    const int total = NIMG * COUT * SP;
    conv_naive<<<(total + 255) / 256, 256, 0, stream>>>(x, w, bias, out);
  }
}